// Round 8
// baseline (323.304 us; speedup 1.0000x reference)
//
#include <hip/hip_runtime.h>

#define N_NODES 262144
#define BM 64
#define NTHREADS 512

typedef short s16x8 __attribute__((ext_vector_type(8)));
typedef float f32x4 __attribute__((ext_vector_type(4)));

// 2 f32 -> packed bf16x2 in one VOP3 (T12 primitive).
static __device__ __forceinline__ unsigned cvtpk(float lo, float hi) {
  unsigned r;
  asm("v_cvt_pk_bf16_f32 %0, %1, %2" : "=v"(r) : "v"(lo), "v"(hi));
  return r;
}

static __device__ __forceinline__ unsigned short f2bf(float f) {
  union { float f; unsigned u; } v; v.f = f;
  unsigned u = v.u;
  u += 0x7FFFu + ((u >> 16) & 1u);   // round-to-nearest-even
  return (unsigned short)(u >> 16);
}

static __device__ __forceinline__ unsigned long long pack4bf(f32x4 v) {
  unsigned u0 = cvtpk(v.x, v.y);
  unsigned u1 = cvtpk(v.z, v.w);
  return (unsigned long long)u0 | ((unsigned long long)u1 << 32);
}

static __device__ __forceinline__ float fsig(float x) {
  return __builtin_amdgcn_rcpf(1.0f + __expf(-x));
}
static __device__ __forceinline__ float ftanh(float x) {
  return 2.0f * __builtin_amdgcn_rcpf(1.0f + __expf(-2.0f * x)) - 1.0f;
}

// async global->LDS DMA, 16B/lane, zero VGPR/VALU cost (G15 / common-mistake #1)
static __device__ __forceinline__ void gload_lds16(const void* g, void* l) {
  __builtin_amdgcn_global_load_lds(
      (const __attribute__((address_space(1))) unsigned*)g,
      (__attribute__((address_space(3))) unsigned*)l, 16, 0, 0);
}

// Weight prep:
//  Wh2[kb][n][ki] (16 x 64 x 32 bf16)  = W_hid[n][kb*32+ki]
//  W2 [kb][n][ki] ( 8 x 512 x 32 bf16) = k<128 ? W_ih[n][k] : W_hh[n][k-128]
//  biasg[512] = b_ih + b_hh
__global__ void prep_kernel(const float* __restrict__ Whid, const float* __restrict__ Wih,
                            const float* __restrict__ Whh, const float* __restrict__ bih,
                            const float* __restrict__ bhh,
                            unsigned short* __restrict__ oWh2, unsigned short* __restrict__ oW2,
                            float* __restrict__ oBias) {
  int t = blockIdx.x * 256 + threadIdx.x;
  if (t < 32768) {
    int kb = t >> 11, n = (t >> 5) & 63, ki = t & 31;
    oWh2[t] = f2bf(Whid[n * 512 + kb * 32 + ki]);
  }
  if (t < 131072) {
    int kb = t >> 14, n = (t >> 5) & 511, ki = t & 31;
    int k = kb * 32 + ki;
    float v = (k < 128) ? Wih[n * 128 + k] : Whh[n * 128 + (k - 128)];
    oW2[t] = f2bf(v);
  }
  if (t < 512) oBias[t] = bih[t] + bhh[t];
}

// bufA: 64 rows x 256 bf16 (512B rows), reused for h0 -> h1 -> A2.
// XOR-swizzle spreads 16-row-strided b128 column reads over 8 16B slots (G4).
#define SWZ(m, b) ((((m) * 512) + (b)) ^ (((m) & 7) << 4))

__global__ __launch_bounds__(NTHREADS, 4) void node_rnn_kernel(
    const float* __restrict__ Hv, const float* __restrict__ hvv,
    const float* __restrict__ xv, const float* __restrict__ hvp,
    const float* __restrict__ cvp, const int* __restrict__ tsm,
    const float* __restrict__ Wpos, const float* __restrict__ bpos,
    const float* __restrict__ bhid,
    const unsigned short* __restrict__ Wh2,
    const unsigned short* __restrict__ W2,
    const float* __restrict__ biasg,
    float* __restrict__ hvo, float* __restrict__ cvo)
{
  __shared__ __align__(16) char lds[65536];
  char* bufA  = lds;            // 32 KB: h0 / h1 / A2 staging (sequential reuse)
  char* cvlds = lds + 32768;    // 32 KB: cv tile, linear [64][128] f32, DMA-filled

  const int tid = threadIdx.x;
  const int w   = tid >> 6;      // wave 0..7
  const int l   = tid & 63;
  const int l15 = l & 15;
  const int lk  = l >> 4;        // k-group 0..3
  const int wr  = w >> 2;        // phase-1 m-half
  const int wc  = w & 3;         // phase-1 n-slice (16 cols)
  const int node0 = blockIdx.x * BM;
  const int d   = 16 * w + l15;  // phase-2/3 gate-dim slice

  // ---- issue cv -> LDS DMA now (zero regs; completes within the pre-B1 burst)
  {
    const char* gbase = (const char*)(cvp + (size_t)node0 * 128);
    int o = w * 4096 + l * 16;
#pragma unroll
    for (int i = 0; i < 4; ++i)
      gload_lds16(gbase + o + i * 1024, cvlds + o + i * 1024);
  }

  // ---- stage h0 = hvv (64 x 256 f32) -> bf16 bufA
  {
#pragma unroll
    for (int it = 0; it < 8; ++it) {
      int p = tid + it * NTHREADS;          // 64 rows x 64 f32x4-chunks
      int m = p >> 6, ch = p & 63;
      f32x4 v = *(const f32x4*)(hvv + (size_t)(node0 + m) * 256 + ch * 4);
      *(unsigned long long*)(bufA + SWZ(m, ch * 8)) = pack4bf(v);
    }
  }

  // ---- small per-tile loads (latency hidden behind the staging burst)
  unsigned long long actmask = __ballot(tsm[node0 + l] == 1);  // bit m = row m active

  unsigned evp[4];     // e_v as packed bf16 pairs
#pragma unroll
  for (int it = 0; it < 4; ++it) {
    int p = tid + it * NTHREADS;            // 64 rows x 32 pairs
    int m = p >> 5, jp = p & 31;
    float x0 = xv[(size_t)(node0 + m) * 2 + 0];
    float x1 = xv[(size_t)(node0 + m) * 2 + 1];
    float e0 = fmaxf(x0 * Wpos[(2*jp  )*2] + x1 * Wpos[(2*jp  )*2+1] + bpos[2*jp  ], 0.f);
    float e1 = fmaxf(x0 * Wpos[(2*jp+1)*2] + x1 * Wpos[(2*jp+1)*2+1] + bpos[2*jp+1], 0.f);
    evp[it] = cvtpk(e0, e1);
  }
  f32x4 hvc[4];        // hv_tm1 for the A2 tile
#pragma unroll
  for (int it = 0; it < 4; ++it) {
    int p = tid + it * NTHREADS;            // 64 rows x 32 f32x4-chunks
    int m = p >> 5, c4 = p & 31;
    hvc[it] = *(const f32x4*)(hvp + (size_t)(node0 + m) * 128 + c4 * 4);
  }

  __syncthreads();   // B1: h0 staged, cv DMA drained (implicit vmcnt0) & published

  // ---- issue h1 = Hv loads into regs; phase-1a MFMAs cover their latency
  f32x4 gv[8];
#pragma unroll
  for (int it = 0; it < 8; ++it) {
    int p = tid + it * NTHREADS;
    int m = p >> 6, ch = p & 63;
    gv[it] = *(const f32x4*)(Hv + (size_t)(node0 + m) * 256 + ch * 4);
  }

  // ---- phase 1a: acc += h0 @ Wh^T (K 0..255). Wave (wr,wc): rows wr*32+[0,32), cols wc*16+[0,16)
  f32x4 acc[2] = {f32x4{0.f,0.f,0.f,0.f}, f32x4{0.f,0.f,0.f,0.f}};
  const char* whb = (const char*)Wh2 + (wc * 16 + l15) * 64 + lk * 16;
#pragma unroll
  for (int ks = 0; ks < 8; ++ks) {
    s16x8 bf = *(const s16x8*)(whb + ks * 4096);
#pragma unroll
    for (int mi = 0; mi < 2; ++mi) {
      s16x8 af = *(const s16x8*)(bufA + SWZ(wr * 32 + mi * 16 + l15, ks * 64 + lk * 16));
      acc[mi] = __builtin_amdgcn_mfma_f32_16x16x32_bf16(af, bf, acc[mi], 0, 0, 0);
    }
  }

  __syncthreads();   // B2: all h0 reads done -> bufA writable

  // ---- stage h1 -> bufA
#pragma unroll
  for (int it = 0; it < 8; ++it) {
    int p = tid + it * NTHREADS;
    int m = p >> 6, ch = p & 63;
    *(unsigned long long*)(bufA + SWZ(m, ch * 8)) = pack4bf(gv[it]);
  }

  __syncthreads();   // B3: h1 staged

  // ---- phase 1b: acc += h1 @ Wh^T (K 256..511)
#pragma unroll
  for (int ks = 0; ks < 8; ++ks) {
    s16x8 bf = *(const s16x8*)(whb + (8 + ks) * 4096);
#pragma unroll
    for (int mi = 0; mi < 2; ++mi) {
      s16x8 af = *(const s16x8*)(bufA + SWZ(wr * 32 + mi * 16 + l15, ks * 64 + lk * 16));
      acc[mi] = __builtin_amdgcn_mfma_f32_16x16x32_bf16(af, bf, acc[mi], 0, 0, 0);
    }
  }

  __syncthreads();   // B4: all h1 reads done -> bufA writable for A2

  // ---- build A2 = [e_v(64) | a_v(64) | hv(128)] bf16 in bufA
#pragma unroll
  for (int it = 0; it < 4; ++it) {
    int p = tid + it * NTHREADS;
    int m = p >> 5, jp = p & 31;
    *(unsigned*)(bufA + SWZ(m, jp * 4)) = evp[it];
  }
#pragma unroll
  for (int it = 0; it < 4; ++it) {
    int p = tid + it * NTHREADS;
    int m = p >> 5, c4 = p & 31;
    *(unsigned long long*)(bufA + SWZ(m, 256 + c4 * 8)) = pack4bf(hvc[it]);
  }
  {
    float bb = bhid[wc * 16 + l15];
    int cb = (64 + wc * 16 + l15) * 2;
#pragma unroll
    for (int mi = 0; mi < 2; ++mi) {
#pragma unroll
      for (int r = 0; r < 4; ++r) {
        int m = wr * 32 + mi * 16 + lk * 4 + r;
        float av = fmaxf(acc[mi][r] + bb, 0.0f);
        *(unsigned short*)(bufA + SWZ(m, cb)) = f2bf(av);
      }
    }
  }
  __syncthreads();   // B5: A2 complete

  float bs[4];
#pragma unroll
  for (int j = 0; j < 4; ++j) bs[j] = biasg[128 * j + d];

  // ---- phase 2: gates = A2(64x256) @ [Wih;Whh]^T; wave w owns d-slice [16w,16w+16) of all 4 gates
  f32x4 acc2[4][4];
#pragma unroll
  for (int mi = 0; mi < 4; ++mi)
#pragma unroll
    for (int j = 0; j < 4; ++j) acc2[mi][j] = f32x4{0.f,0.f,0.f,0.f};

#pragma unroll
  for (int kk = 0; kk < 8; ++kk) {
    s16x8 a[4];
#pragma unroll
    for (int mi = 0; mi < 4; ++mi)
      a[mi] = *(const s16x8*)(bufA + SWZ(mi * 16 + l15, kk * 64 + lk * 16));
    const char* wb = (const char*)W2 + kk * 32768 + lk * 16;
#pragma unroll
    for (int j = 0; j < 4; ++j) {
      s16x8 bf = *(const s16x8*)(wb + (size_t)(16 * w + 128 * j + l15) * 64);
#pragma unroll
      for (int mi = 0; mi < 4; ++mi)
        acc2[mi][j] = __builtin_amdgcn_mfma_f32_16x16x32_bf16(a[mi], bf, acc2[mi][j], 0, 0, 0);
    }
  }

  // ---- phase 3: LSTM pointwise + mask select. cv from LDS, hv re-read L1/L2-hot.
#pragma unroll
  for (int mi = 0; mi < 4; ++mi) {
#pragma unroll
    for (int r = 0; r < 4; ++r) {
      int m = mi * 16 + lk * 4 + r;
      size_t node = (size_t)node0 + m;
      int act = (int)((actmask >> m) & 1ull);
      float gi = acc2[mi][0][r] + bs[0];
      float gf = acc2[mi][1][r] + bs[1];
      float gg = acc2[mi][2][r] + bs[2];
      float go = acc2[mi][3][r] + bs[3];
      float i_ = fsig(gi), f_ = fsig(gf), o_ = fsig(go);
      float g_ = ftanh(gg);
      float co = *(const float*)(cvlds + m * 512 + d * 4);
      float ho = hvp[node * 128 + d];
      float cn = f_ * co + i_ * g_;
      float hn = o_ * ftanh(cn);
      hvo[node * 128 + d] = act ? hn : ho;
      cvo[node * 128 + d] = act ? cn : co;
    }
  }
}

extern "C" void kernel_launch(void* const* d_in, const int* in_sizes, int n_in,
                              void* d_out, int out_size, void* d_ws, size_t ws_size,
                              hipStream_t stream) {
  const float* Hv   = (const float*)d_in[0];
  const float* hvv  = (const float*)d_in[1];
  const float* xv   = (const float*)d_in[2];
  const float* hvp  = (const float*)d_in[3];
  const float* cvp  = (const float*)d_in[4];
  const int*   tsm  = (const int*)d_in[5];
  const float* Wpos = (const float*)d_in[6];
  const float* bpos = (const float*)d_in[7];
  const float* Whid = (const float*)d_in[8];
  const float* bhid = (const float*)d_in[9];
  const float* Wih  = (const float*)d_in[10];
  const float* bih  = (const float*)d_in[11];
  const float* Whh  = (const float*)d_in[12];
  const float* bhh  = (const float*)d_in[13];

  unsigned short* wsWh2 = (unsigned short*)d_ws;   // 32768 bf16
  unsigned short* wsW2  = wsWh2 + 32768;           // 131072 bf16
  float* wsBias = (float*)(wsW2 + 131072);         // 512 f32

  prep_kernel<<<512, 256, 0, stream>>>(Whid, Wih, Whh, bih, bhh,
                                       wsWh2, wsW2, wsBias);

  float* hvo = (float*)d_out;
  float* cvo = hvo + (size_t)N_NODES * 128;
  node_rnn_kernel<<<N_NODES / BM, NTHREADS, 0, stream>>>(
      Hv, hvv, xv, hvp, cvp, tsm, Wpos, bpos, bhid,
      wsWh2, wsW2, wsBias, hvo, cvo);
}

// Round 9
// 290.240 us; speedup vs baseline: 1.1139x; 1.1139x over previous
//
#include <hip/hip_runtime.h>

#define N_NODES 262144
#define BM 64
#define NTHREADS 512

typedef short s16x8 __attribute__((ext_vector_type(8)));
typedef float f32x4 __attribute__((ext_vector_type(4)));

// 2 f32 -> packed bf16x2 in one VOP3 (T12 primitive).
static __device__ __forceinline__ unsigned cvtpk(float lo, float hi) {
  unsigned r;
  asm("v_cvt_pk_bf16_f32 %0, %1, %2" : "=v"(r) : "v"(lo), "v"(hi));
  return r;
}

static __device__ __forceinline__ unsigned short f2bf(float f) {
  union { float f; unsigned u; } v; v.f = f;
  unsigned u = v.u;
  u += 0x7FFFu + ((u >> 16) & 1u);   // round-to-nearest-even
  return (unsigned short)(u >> 16);
}

static __device__ __forceinline__ float fsig(float x) {
  return __builtin_amdgcn_rcpf(1.0f + __expf(-x));
}
static __device__ __forceinline__ float ftanh(float x) {
  return 2.0f * __builtin_amdgcn_rcpf(1.0f + __expf(-2.0f * x)) - 1.0f;
}

// async global->LDS DMA, 16B/lane/call: per-lane global src, wave-uniform LDS base (m104)
static __device__ __forceinline__ void gload_lds16(const float* g, char* l) {
  __builtin_amdgcn_global_load_lds(
      (const __attribute__((address_space(1))) unsigned*)g,
      (__attribute__((address_space(3))) unsigned*)l, 16, 0, 0);
}

// Weight prep:
//  Wh2[kb][n][ki] (16 x 64 x 32 bf16)  = W_hid[n][kb*32+ki]
//  W2 [kb][n][ki] ( 8 x 512 x 32 bf16) = k<128 ? W_ih[n][k] : W_hh[n][k-128]
//  biasg[512] = b_ih + b_hh
__global__ void prep_kernel(const float* __restrict__ Whid, const float* __restrict__ Wih,
                            const float* __restrict__ Whh, const float* __restrict__ bih,
                            const float* __restrict__ bhh,
                            unsigned short* __restrict__ oWh2, unsigned short* __restrict__ oW2,
                            float* __restrict__ oBias) {
  int t = blockIdx.x * 256 + threadIdx.x;
  if (t < 32768) {
    int kb = t >> 11, n = (t >> 5) & 63, ki = t & 31;
    oWh2[t] = f2bf(Whid[n * 512 + kb * 32 + ki]);
  }
  if (t < 131072) {
    int kb = t >> 14, n = (t >> 5) & 511, ki = t & 31;
    int k = kb * 32 + ki;
    float v = (k < 128) ? Wih[n * 128 + k] : Whh[n * 128 + (k - 128)];
    oW2[t] = f2bf(v);
  }
  if (t < 512) oBias[t] = bih[t] + bhh[t];
}

// f32 stage quarter: [64 rows][128 f32] = 512B rows; data for (row r, 16B-chunk j)
// lives at chunk (j ^ (r&7)) — XOR applied on DMA *source*, re-applied on read (G4/m173).
// A2: 64 rows x 256 bf16 (512B rows) = [e_v(64)|a_v(64)|hv(128)], aliases stage0.
#define SWZ2(m, b) ((((m) * 512) + (b)) ^ (((m) & 7) << 4))

__global__ __launch_bounds__(NTHREADS, 4) void node_rnn_kernel(
    const float* __restrict__ Hv, const float* __restrict__ hvv,
    const float* __restrict__ xv, const float* __restrict__ hvp,
    const float* __restrict__ cvp, const int* __restrict__ tsm,
    const float* __restrict__ Wpos, const float* __restrict__ bpos,
    const float* __restrict__ bhid,
    const unsigned short* __restrict__ Wh2,
    const unsigned short* __restrict__ W2,
    const float* __restrict__ biasg,
    float* __restrict__ hvo, float* __restrict__ cvo)
{
  __shared__ __align__(16) char lds[65536];   // stage0=lds[0:32K] (later A2), stage1=lds[32K:64K]

  const int tid = threadIdx.x;
  const int w   = tid >> 6;      // wave 0..7
  const int l   = tid & 63;
  const int l15 = l & 15;
  const int lk  = l >> 4;        // k-group 0..3
  const int wr  = w >> 2;        // phase-1 m-half
  const int wc  = w & 3;         // phase-1 n-slice (16 cols)
  const int node0 = blockIdx.x * BM;
  const int d   = 16 * w + l15;  // phase-2/3 gate-dim slice

  // ---- pre-DMA loads: everything consumed before B0 must be OLDER than the DMA
  int mts = tsm[node0 + l];                       // coalesced
  float xa[4], xb[4];
  f32x4 wps[4];
  float bp0[4], bp1[4];
#pragma unroll
  for (int it = 0; it < 4; ++it) {
    int p = tid + it * NTHREADS;
    int m = p >> 5, jp = p & 31;
    xa[it] = xv[(size_t)(node0 + m) * 2 + 0];
    xb[it] = xv[(size_t)(node0 + m) * 2 + 1];
    wps[it] = *(const f32x4*)(Wpos + 4 * jp);     // rows 2jp,2jp+1 of Wpos
    bp0[it] = bpos[2 * jp]; bp1[it] = bpos[2 * jp + 1];
  }

  // ---- issue DMA q0 (hvv cols 0..127) -> stage0
#pragma unroll
  for (int i = 0; i < 4; ++i) {
    int o = w * 4096 + i * 1024 + l * 16;
    int r = o >> 9;
    int c = ((o >> 4) & 31) ^ (r & 7);
    gload_lds16(hvv + (size_t)(node0 + r) * 256 + c * 4, lds + w * 4096 + i * 1024);
  }

  // ---- hv_tm1 prefetch (consumed after several barriers; drain cost absorbed by B0)
  f32x4 hvc[4];
#pragma unroll
  for (int it = 0; it < 4; ++it) {
    int p = tid + it * NTHREADS;
    int m = p >> 5, c4 = p & 31;
    hvc[it] = *(const f32x4*)(hvp + (size_t)(node0 + m) * 128 + c4 * 4);
  }

  // ---- e_v compute (xv/Wpos/bpos all older than DMA -> no DMA drain)
  unsigned evp[4];
#pragma unroll
  for (int it = 0; it < 4; ++it) {
    float e0 = fmaxf(xa[it] * wps[it].x + xb[it] * wps[it].y + bp0[it], 0.f);
    float e1 = fmaxf(xa[it] * wps[it].z + xb[it] * wps[it].w + bp1[it], 0.f);
    evp[it] = cvtpk(e0, e1);
  }
  unsigned long long actmask = __ballot(mts == 1);   // tsm older than DMA

  __syncthreads();   // B0: q0 staged (vmcnt drain), hvc landed

  // ---- phase 1: 4-quarter DMA pipeline. acc += [hvv|Hv] @ Wh^T
  f32x4 acc[2] = {f32x4{0.f,0.f,0.f,0.f}, f32x4{0.f,0.f,0.f,0.f}};
  const char* whb = (const char*)Wh2 + (wc * 16 + l15) * 64 + lk * 16;

#pragma unroll
  for (int q = 0; q < 4; ++q) {
    char* stq = lds + ((q & 1) << 15);

    // weight prefetch for this quarter FIRST (older than next DMA -> no drain)
    s16x8 wq[4];
#pragma unroll
    for (int ks = 0; ks < 4; ++ks)
      wq[ks] = *(const s16x8*)(whb + (q * 4 + ks) * 4096);

    if (q < 3) {
      // issue next-quarter DMA; its completion is enforced by this quarter's barrier
      char* dst = lds + (((q + 1) & 1) << 15);
      const float* srcb = ((q + 1) < 2) ? hvv : Hv;
      int colb = ((q + 1) & 1) * 128;
#pragma unroll
      for (int i = 0; i < 4; ++i) {
        int o = w * 4096 + i * 1024 + l * 16;
        int r = o >> 9;
        int c = ((o >> 4) & 31) ^ (r & 7);
        gload_lds16(srcb + (size_t)(node0 + r) * 256 + colb + c * 4,
                    dst + w * 4096 + i * 1024);
      }
    } else {
      // q==3: write A2 e_v + hv into stage0 (q2 reads finished at the q2 barrier;
      // disjoint from q3's stage1 reads and from a_v cols)
#pragma unroll
      for (int it = 0; it < 4; ++it) {
        int p = tid + it * NTHREADS;
        int m = p >> 5, jp = p & 31;
        *(unsigned*)(lds + SWZ2(m, jp * 4)) = evp[it];
      }
#pragma unroll
      for (int it = 0; it < 4; ++it) {
        int p = tid + it * NTHREADS;
        int m = p >> 5, c4 = p & 31;
        f32x4 v = hvc[it];
        unsigned u0 = cvtpk(v.x, v.y), u1 = cvtpk(v.z, v.w);
        unsigned long long uu = (unsigned long long)u0 | ((unsigned long long)u1 << 32);
        *(unsigned long long*)(lds + SWZ2(m, 256 + c4 * 8)) = uu;
      }
    }

    // MFMA on quarter q: read f32 frags from LDS, cvt_pk on the fly
#pragma unroll
    for (int ks = 0; ks < 4; ++ks) {
#pragma unroll
      for (int mi = 0; mi < 2; ++mi) {
        int m = wr * 32 + mi * 16 + l15;
        int c0 = ks * 8 + lk * 2;
        int a0 = m * 512 + ((c0 ^ (m & 7)) * 16);
        int a1 = m * 512 + (((c0 + 1) ^ (m & 7)) * 16);
        f32x4 A0 = *(const f32x4*)(stq + a0);
        f32x4 A1 = *(const f32x4*)(stq + a1);
        union { unsigned u[4]; s16x8 v; } t;
        t.u[0] = cvtpk(A0.x, A0.y); t.u[1] = cvtpk(A0.z, A0.w);
        t.u[2] = cvtpk(A1.x, A1.y); t.u[3] = cvtpk(A1.z, A1.w);
        acc[mi] = __builtin_amdgcn_mfma_f32_16x16x32_bf16(t.v, wq[ks], acc[mi], 0, 0, 0);
      }
    }

    if (q < 3) __syncthreads();   // q+1 staged & q reads done
  }

  // ---- a_v -> A2 (own-wave acc; disjoint cols, no barrier needed before)
  {
    float bb = bhid[wc * 16 + l15];
    int cb = (64 + wc * 16 + l15) * 2;
#pragma unroll
    for (int mi = 0; mi < 2; ++mi) {
#pragma unroll
      for (int r = 0; r < 4; ++r) {
        int m = wr * 32 + mi * 16 + lk * 4 + r;
        float av = fmaxf(acc[mi][r] + bb, 0.0f);
        *(unsigned short*)(lds + SWZ2(m, cb)) = f2bf(av);
      }
    }
  }
  __syncthreads();   // B4: A2 complete

  float bs[4];
#pragma unroll
  for (int j = 0; j < 4; ++j) bs[j] = biasg[128 * j + d];

  // ---- phase 2: gates = A2(64x256) @ [Wih;Whh]^T; wave w owns d-slice [16w,16w+16) of all 4 gates
  f32x4 acc2[4][4];
#pragma unroll
  for (int mi = 0; mi < 4; ++mi)
#pragma unroll
    for (int j = 0; j < 4; ++j) acc2[mi][j] = f32x4{0.f,0.f,0.f,0.f};

#pragma unroll
  for (int kk = 0; kk < 8; ++kk) {
    s16x8 a[4];
#pragma unroll
    for (int mi = 0; mi < 4; ++mi)
      a[mi] = *(const s16x8*)(lds + SWZ2(mi * 16 + l15, kk * 64 + lk * 16));
    const char* wb = (const char*)W2 + kk * 32768 + lk * 16;
#pragma unroll
    for (int j = 0; j < 4; ++j) {
      s16x8 bf = *(const s16x8*)(wb + (size_t)(16 * w + 128 * j + l15) * 64);
#pragma unroll
      for (int mi = 0; mi < 4; ++mi)
        acc2[mi][j] = __builtin_amdgcn_mfma_f32_16x16x32_bf16(a[mi], bf, acc2[mi][j], 0, 0, 0);
    }
  }

  // ---- phase 3: LSTM pointwise + mask select
#pragma unroll
  for (int mi = 0; mi < 4; ++mi) {
#pragma unroll
    for (int r = 0; r < 4; ++r) {
      int m = mi * 16 + lk * 4 + r;
      size_t node = (size_t)node0 + m;
      int act = (int)((actmask >> m) & 1ull);
      float gi = acc2[mi][0][r] + bs[0];
      float gf = acc2[mi][1][r] + bs[1];
      float gg = acc2[mi][2][r] + bs[2];
      float go = acc2[mi][3][r] + bs[3];
      float i_ = fsig(gi), f_ = fsig(gf), o_ = fsig(go);
      float g_ = ftanh(gg);
      float co = cvp[node * 128 + d];
      float ho = hvp[node * 128 + d];
      float cn = f_ * co + i_ * g_;
      float hn = o_ * ftanh(cn);
      hvo[node * 128 + d] = act ? hn : ho;
      cvo[node * 128 + d] = act ? cn : co;
    }
  }
}

extern "C" void kernel_launch(void* const* d_in, const int* in_sizes, int n_in,
                              void* d_out, int out_size, void* d_ws, size_t ws_size,
                              hipStream_t stream) {
  const float* Hv   = (const float*)d_in[0];
  const float* hvv  = (const float*)d_in[1];
  const float* xv   = (const float*)d_in[2];
  const float* hvp  = (const float*)d_in[3];
  const float* cvp  = (const float*)d_in[4];
  const int*   tsm  = (const int*)d_in[5];
  const float* Wpos = (const float*)d_in[6];
  const float* bpos = (const float*)d_in[7];
  const float* Whid = (const float*)d_in[8];
  const float* bhid = (const float*)d_in[9];
  const float* Wih  = (const float*)d_in[10];
  const float* bih  = (const float*)d_in[11];
  const float* Whh  = (const float*)d_in[12];
  const float* bhh  = (const float*)d_in[13];

  unsigned short* wsWh2 = (unsigned short*)d_ws;   // 32768 bf16
  unsigned short* wsW2  = wsWh2 + 32768;           // 131072 bf16
  float* wsBias = (float*)(wsW2 + 131072);         // 512 f32

  prep_kernel<<<512, 256, 0, stream>>>(Whid, Wih, Whh, bih, bhh,
                                       wsWh2, wsW2, wsBias);

  float* hvo = (float*)d_out;
  float* cvo = hvo + (size_t)N_NODES * 128;
  node_rnn_kernel<<<N_NODES / BM, NTHREADS, 0, stream>>>(
      Hv, hvv, xv, hvp, cvp, tsm, Wpos, bpos, bhid,
      wsWh2, wsW2, wsBias, hvo, cvo);
}